// Round 22
// baseline (119.591 us; speedup 1.0000x reference)
//
#include <hip/hip_runtime.h>

// out[b] = ||xd_b||^2 - (s_b . xd_b)^2 / (1 + ||s_b||^2), s = x @ W^T.
// R22: = R21 (best: 114.2 us; GEMM 86) with ONE change: full-iteration DMA
// lead WITHOUT extra LDS. Old loop staged t+1 at iter-t start and drained it
// ~500 cyc later (WAITV(0)) -> per-CU L2 DMA demand (3 blk x 16 KB ~ 900 cyc
// BW + 300 cyc latency) left several hundred cycles exposed per iteration.
// New rotation: read frags(t) from buf(t&1); lgkm0; BARRIER (all waves done
// reading); stage t+2 INTO buf(t&1); MFMA; WAITV(4) -> t+1 (issued a full
// iteration ago) landed, t+2 flying; BARRIER. LDS stays 32 KiB -> 3 blocks/CU
// preserved (R14's 3-buffer attempt lost a block to LDS granularity).
// Tail ledger: iter 14 stages clamp(16)=15 -> buf0 (unread after); iter 15
// stages clamp(17)=15 -> buf1 AFTER all reads drained, and bytes are
// identical to what's there (tile 15) -- doubly safe. Final WAITV(0) after
// epilogue drains clamped tails before exit.

#define MTOT 16384
#define DTOT 2048
#define NK 16   // K-tiles of 128

typedef unsigned char u8;
typedef __attribute__((ext_vector_type(4))) float f32x4;
typedef __attribute__((ext_vector_type(8))) int i32x8;

// f32 -> OCP e2m1 (fp4), RNE, saturating. Values {0,.5,1,1.5,2,3,4,6}.
__device__ __forceinline__ unsigned f2e2m1(float f) {
    unsigned sgn = f < 0.f ? 8u : 0u;
    float a = fabsf(f);
    unsigned c;
    if      (a < 0.25f) c = 0;
    else if (a < 0.75f) c = 1;
    else if (a < 1.25f) c = 2;
    else if (a < 1.75f) c = 3;
    else if (a < 2.5f)  c = 4;
    else if (a < 3.5f)  c = 5;
    else if (a < 5.0f)  c = 6;
    else                c = 7;
    return sgn | c;
}

__device__ __forceinline__ void gload_lds16(const void* gptr, void* ldsptr) {
    __builtin_amdgcn_global_load_lds(
        (const __attribute__((address_space(1))) unsigned int*)gptr,
        (__attribute__((address_space(3))) unsigned int*)ldsptr,
        16, 0, 0);
}

#define BARS()   __builtin_amdgcn_s_barrier()
#define SCHED0() __builtin_amdgcn_sched_barrier(0)
#define LGKM0()  asm volatile("s_waitcnt lgkmcnt(0)")
#define WAITV(n) asm volatile("s_waitcnt vmcnt(" #n ")")

// ------------- cast f32 -> fp4, x and W in ONE launch (8 elems/thread) -------------
__global__ void cast4two_kernel(const float* __restrict__ x, const float* __restrict__ W,
                                unsigned* __restrict__ xq, unsigned* __restrict__ wq,
                                int nx8, int ntot8) {
    int stride = gridDim.x * blockDim.x;
    for (int i = blockIdx.x * blockDim.x + threadIdx.x; i < ntot8; i += stride) {
        const float* s; unsigned* d; int j; float mul;
        if (i < nx8) { s = x; d = xq; j = i; mul = 1.0f; }
        else         { s = W; d = wq; j = i - nx8; mul = 64.0f; }
        f32x4 v0 = ((const f32x4*)s)[2 * (size_t)j];
        f32x4 v1 = ((const f32x4*)s)[2 * (size_t)j + 1];
        d[j] =  f2e2m1(v0[0] * mul)        | (f2e2m1(v0[1] * mul) << 4)  |
               (f2e2m1(v0[2] * mul) << 8)  | (f2e2m1(v0[3] * mul) << 12) |
               (f2e2m1(v1[0] * mul) << 16) | (f2e2m1(v1[1] * mul) << 20) |
               (f2e2m1(v1[2] * mul) << 24) | (f2e2m1(v1[3] * mul) << 28);
    }
}

// ---------------- fp4 128^2 GEMM + fused reductions ----------------
// grid = 2048 blocks x 256 threads (4 waves, 2x2). Per wave 64x64 = acc[4][4];
// one mfma_scale_16x16x128 (FMT=4) per frag per kt.
// LDS 32 KiB: [2 buf][A 8 KiB | B 8 KiB]; region = [64 lines][128 B], line L
// holds rows 2L,2L+1 (64 B each = 4x16B units), phys slot = q ^ (L&7),
// q = ((row&1)<<2)|unit -> frag b128 reads 2-way fold only (0 conflicts).
// XCD map: XCD k = bid%8 owns brow panels [16k,16k+16) (2.1 MB x,
// L2-resident); bcol sweeps slowest.
__global__ __launch_bounds__(256, 3)
void gemmf4(const u8* __restrict__ xq, const u8* __restrict__ wq,
            const float* __restrict__ xdot,
            float* __restrict__ ns_acc, float* __restrict__ sx_acc,
            float* __restrict__ xx_acc) {
    __shared__ u8 lds[32768];

    const int tid  = threadIdx.x;
    const int lane = tid & 63;
    const int wid  = tid >> 6;
    const int wr = wid >> 1, wc = wid & 1;   // 2 x 2 wave grid
    const int fr = lane & 15, fq = lane >> 4;

    const int bid = blockIdx.x;              // 2048
    const int brow = ((bid & 7) * 16 + ((bid >> 3) & 15)) * 128;  // XCD-local x slice
    const int bcol = (bid >> 7) * 128;                            // sweeps slowest

    const int RS = DTOT / 2;   // row stride in fp4 bytes = 1024

    auto stage_region = [&](const u8* src, int region) {
#pragma unroll
        for (int c2 = 0; c2 < 2; ++c2) {
            const int c = c2 * 256 + tid;
            const int L = c >> 3, p = c & 7;
            const int q = p ^ (L & 7);
            gload_lds16(src + (size_t)(2 * L + (q >> 2)) * RS + (q & 3) * 16,
                        (char*)lds + region + c * 16);
        }
    };
    auto stage_tile = [&](int kt, int bufbyte) {
        const int kb = kt * 64;              // 128 k-elems = 64 B
        stage_region(xq + (size_t)brow * RS + kb, bufbyte);
        stage_region(wq + (size_t)bcol * RS + kb, bufbyte + 8192);
    };

    auto rdfrag = [&](int region, int row) -> int4 {
        const int L = row >> 1;
        const int p = ((((row & 1) << 2) | fq) ^ (L & 7));
        return *(const int4*)((const char*)lds + region + L * 128 + (p << 4));
    };
    auto mk8 = [](int4 v) -> i32x8 {
        i32x8 r;
        r[0] = v.x; r[1] = v.y; r[2] = v.z; r[3] = v.w;
        r[4] = 0;   r[5] = 0;   r[6] = 0;   r[7] = 0;
        return r;
    };

    f32x4 acc[4][4] = {};
    int4 af[4], bf[4];

    // ---- prologue: tiles 0 and 1 (2-deep from the start)
    stage_tile(0, 0);
    stage_tile(1, 16384);
    WAITV(4);   // tile 0 landed; tile 1's 4 in flight
    SCHED0(); BARS();

    for (int t = 0; t < NK; ++t) {
        const int buf = (t & 1) * 16384;

        // read ALL frags of tile t (must complete before buf is restaged)
#pragma unroll
        for (int n = 0; n < 4; ++n) bf[n] = rdfrag(buf + 8192, wc * 64 + n * 16 + fr);
#pragma unroll
        for (int m = 0; m < 4; ++m) af[m] = rdfrag(buf, wr * 64 + m * 16 + fr);
        LGKM0();    // own reads in regs
        SCHED0(); BARS();   // ALL waves done reading buf -> safe to overwrite

        {   // stage tile t+2 into buf (clamped tail: rewrites identical bytes)
            const int v = t + 2 > NK - 1 ? NK - 1 : t + 2;
            stage_tile(v, buf);
        }
        SCHED0();
        __builtin_amdgcn_s_setprio(1);
#pragma unroll
        for (int m = 0; m < 4; ++m)
#pragma unroll
            for (int n = 0; n < 4; ++n)
                acc[m][n] = __builtin_amdgcn_mfma_scale_f32_16x16x128_f8f6f4(
                    mk8(af[m]), mk8(bf[n]), acc[m][n],
                    4, 4,                    // cbsz = blgp = 4 -> fp4 e2m1
                    0, 0x7f7f7f7f,           // scale A = 1.0 (e8m0)
                    0, 0x7f7f7f7f);          // scale B = 1.0
        __builtin_amdgcn_s_setprio(0);
        // t+1's DMA was issued a FULL iteration ago -> latency+queue covered
        WAITV(4);   // drain t+1 (own ops); t+2 stays in flight
        SCHED0(); BARS();   // collective: buf(t+1) fully published
    }

    // Epilogue: C/D col = lane&15, row = (lane>>4)*4 + reg (shape-determined).
    // Reduce s^2, s*xd, xd^2 over fr; 1 atomicAdd/row/qty/wave.
#pragma unroll
    for (int m = 0; m < 4; ++m) {
#pragma unroll
        for (int jj = 0; jj < 4; ++jj) {
            const int row = brow + wr * 64 + m * 16 + fq * 4 + jj;
            const float* xp = xdot + (size_t)row * DTOT + bcol + wc * 64 + fr;
            float pns = 0.f, psx = 0.f, pxx = 0.f;
#pragma unroll
            for (int n = 0; n < 4; ++n) {
                float s  = acc[m][n][jj];   // = 64 * s_true
                float xv = xp[n * 16];
                pns += s * s; psx += s * xv; pxx += xv * xv;
            }
#pragma unroll
            for (int msk = 1; msk < 16; msk <<= 1) {
                pns += __shfl_xor(pns, msk);
                psx += __shfl_xor(psx, msk);
                pxx += __shfl_xor(pxx, msk);
            }
            if (fr == 0) {
                atomicAdd(&ns_acc[row], pns);
                atomicAdd(&sx_acc[row], psx);
                atomicAdd(&xx_acc[row], pxx);
            }
        }
    }
    WAITV(0);   // drain clamped tail DMA before LDS dealloc at exit
}

__global__ void finalize_k(const float* __restrict__ ns, const float* __restrict__ sx,
                           const float* __restrict__ xx, float* __restrict__ out) {
    int i = blockIdx.x * blockDim.x + threadIdx.x;
    // ns,sx carry the x64 W-prescale: sx_true^2/(1+ns_true) = sx^2/(4096+ns)
    if (i < MTOT) out[i] = xx[i] - (sx[i] * sx[i]) / (4096.0f + ns[i]);
}

extern "C" void kernel_launch(void* const* d_in, const int* in_sizes, int n_in,
                              void* d_out, int out_size, void* d_ws, size_t ws_size,
                              hipStream_t stream) {
    const float* x  = (const float*)d_in[0];
    const float* xd = (const float*)d_in[1];
    const float* W  = (const float*)d_in[2];
    float* out = (float*)d_out;

    const size_t xq_bytes = (size_t)MTOT * DTOT / 2;   // 16.8 MB fp4
    const size_t wq_bytes = (size_t)DTOT * DTOT / 2;   //  2.1 MB fp4
    const size_t acc_bytes = (size_t)3 * MTOT * 4;     //  0.2 MB

    u8* xq = (u8*)d_ws;
    u8* wq = (u8*)((char*)d_ws + xq_bytes);
    float* accs = (float*)((char*)d_ws + xq_bytes + wq_bytes);
    float* nsA = accs;
    float* sxA = accs + MTOT;
    float* xxA = accs + 2 * MTOT;
    (void)ws_size; (void)in_sizes; (void)n_in; (void)out_size;

    hipMemsetAsync(accs, 0, acc_bytes, stream);  // re-zero every call

    const int nx8 = MTOT * DTOT / 8, nw8 = DTOT * DTOT / 8;
    cast4two_kernel<<<2048, 256, 0, stream>>>(x, W, (unsigned*)xq, (unsigned*)wq,
                                              nx8, nx8 + nw8);
    gemmf4<<<2048, 256, 0, stream>>>(xq, wq, xd, nsA, sxA, xxA);
    finalize_k<<<MTOT / 256, 256, 0, stream>>>(nsA, sxA, xxA, out);
}

// Round 23
// 108.434 us; speedup vs baseline: 1.1029x; 1.1029x over previous
//
#include <hip/hip_runtime.h>

// out[b] = ||xd_b||^2 - (s_b . xd_b)^2 / (1 + ||s_b||^2), s = x @ W^T.
// R23: FINAL CONSOLIDATION. GEMM = R21/R17's exact best-measured kernel
// (86 us GEMM, 114.2 us total; VGPR 60, zero spill, zero bank conflicts,
// FETCH 90 MB, 3 blocks/CU). R22's rotation regressed (extra barrier +
// read->restage coupling) -> reverted. Only change vs R21: accumulator
// zeroing folded into the cast kernel (grid-stride pre-loop, stream-ordered
// before the GEMM) -- removes the hipMemsetAsync dispatch.
// MX-fp4 e2m1, fixed scales=1.0, W x64 -> finalize /(4096+ns). 128^2 tile,
// 4 waves 2x2, acc[4][4], 32 KiB dbuf, 2-phase loop, XCD k owns brow panels
// [16k,16k+16) (2.1 MB x slice, L2-resident; bcol sweeps slowest).
// Session ladder (total us): 255 bf16-128^2 -> 213 bf16-8phase -> 162 fp8 ->
// 157 fp8-256^2 -> 125 fp4-TLP -> 117.7 fp4+XCD-L2 -> 114.2 consolidated.

#define MTOT 16384
#define DTOT 2048
#define NK 16   // K-tiles of 128

typedef unsigned char u8;
typedef __attribute__((ext_vector_type(4))) float f32x4;
typedef __attribute__((ext_vector_type(8))) int i32x8;

// f32 -> OCP e2m1 (fp4), RNE, saturating. Values {0,.5,1,1.5,2,3,4,6}.
__device__ __forceinline__ unsigned f2e2m1(float f) {
    unsigned sgn = f < 0.f ? 8u : 0u;
    float a = fabsf(f);
    unsigned c;
    if      (a < 0.25f) c = 0;
    else if (a < 0.75f) c = 1;
    else if (a < 1.25f) c = 2;
    else if (a < 1.75f) c = 3;
    else if (a < 2.5f)  c = 4;
    else if (a < 3.5f)  c = 5;
    else if (a < 5.0f)  c = 6;
    else                c = 7;
    return sgn | c;
}

__device__ __forceinline__ void gload_lds16(const void* gptr, void* ldsptr) {
    __builtin_amdgcn_global_load_lds(
        (const __attribute__((address_space(1))) unsigned int*)gptr,
        (__attribute__((address_space(3))) unsigned int*)ldsptr,
        16, 0, 0);
}

#define BARS()   __builtin_amdgcn_s_barrier()
#define SCHED0() __builtin_amdgcn_sched_barrier(0)
#define LGKM0()  asm volatile("s_waitcnt lgkmcnt(0)")
#define WAITV(n) asm volatile("s_waitcnt vmcnt(" #n ")")

// ---- cast f32 -> fp4 (x and W, one launch) + zero the accumulator arrays ----
__global__ void cast4two_kernel(const float* __restrict__ x, const float* __restrict__ W,
                                unsigned* __restrict__ xq, unsigned* __restrict__ wq,
                                float* __restrict__ accs, int nacc,
                                int nx8, int ntot8) {
    int stride = gridDim.x * blockDim.x;
    int gid = blockIdx.x * blockDim.x + threadIdx.x;
    for (int k = gid; k < nacc; k += stride) accs[k] = 0.f;   // replaces memset
    for (int i = gid; i < ntot8; i += stride) {
        const float* s; unsigned* d; int j; float mul;
        if (i < nx8) { s = x; d = xq; j = i; mul = 1.0f; }
        else         { s = W; d = wq; j = i - nx8; mul = 64.0f; }
        f32x4 v0 = ((const f32x4*)s)[2 * (size_t)j];
        f32x4 v1 = ((const f32x4*)s)[2 * (size_t)j + 1];
        d[j] =  f2e2m1(v0[0] * mul)        | (f2e2m1(v0[1] * mul) << 4)  |
               (f2e2m1(v0[2] * mul) << 8)  | (f2e2m1(v0[3] * mul) << 12) |
               (f2e2m1(v1[0] * mul) << 16) | (f2e2m1(v1[1] * mul) << 20) |
               (f2e2m1(v1[2] * mul) << 24) | (f2e2m1(v1[3] * mul) << 28);
    }
}

// ---------------- fp4 128^2 GEMM + fused reductions (R17/R21 verbatim) ----------------
// grid = 2048 blocks x 256 threads (4 waves, 2x2). Per wave 64x64 = acc[4][4];
// one mfma_scale_16x16x128 (FMT=4) per frag per kt.
// LDS 32 KiB: [2 buf][A 8 KiB | B 8 KiB]; region = [64 lines][128 B], line L
// holds rows 2L,2L+1 (64 B each = 4x16B units), phys slot = q ^ (L&7),
// q = ((row&1)<<2)|unit -> frag b128 reads 2-way fold only (0 conflicts).
__global__ __launch_bounds__(256, 3)
void gemmf4(const u8* __restrict__ xq, const u8* __restrict__ wq,
            const float* __restrict__ xdot,
            float* __restrict__ ns_acc, float* __restrict__ sx_acc,
            float* __restrict__ xx_acc) {
    __shared__ u8 lds[32768];

    const int tid  = threadIdx.x;
    const int lane = tid & 63;
    const int wid  = tid >> 6;
    const int wr = wid >> 1, wc = wid & 1;   // 2 x 2 wave grid
    const int fr = lane & 15, fq = lane >> 4;

    const int bid = blockIdx.x;              // 2048
    const int brow = ((bid & 7) * 16 + ((bid >> 3) & 15)) * 128;  // XCD-local x slice
    const int bcol = (bid >> 7) * 128;                            // sweeps slowest

    const int RS = DTOT / 2;   // row stride in fp4 bytes = 1024

    auto stage_region = [&](const u8* src, int region) {
#pragma unroll
        for (int c2 = 0; c2 < 2; ++c2) {
            const int c = c2 * 256 + tid;
            const int L = c >> 3, p = c & 7;
            const int q = p ^ (L & 7);
            gload_lds16(src + (size_t)(2 * L + (q >> 2)) * RS + (q & 3) * 16,
                        (char*)lds + region + c * 16);
        }
    };
    auto stage_tile = [&](int kt, int bufbyte) {
        const int kb = kt * 64;              // 128 k-elems = 64 B
        stage_region(xq + (size_t)brow * RS + kb, bufbyte);
        stage_region(wq + (size_t)bcol * RS + kb, bufbyte + 8192);
    };

    auto rdfrag = [&](int region, int row) -> int4 {
        const int L = row >> 1;
        const int p = ((((row & 1) << 2) | fq) ^ (L & 7));
        return *(const int4*)((const char*)lds + region + L * 128 + (p << 4));
    };
    auto mk8 = [](int4 v) -> i32x8 {
        i32x8 r;
        r[0] = v.x; r[1] = v.y; r[2] = v.z; r[3] = v.w;
        r[4] = 0;   r[5] = 0;   r[6] = 0;   r[7] = 0;
        return r;
    };

    f32x4 acc[4][4] = {};
    int4 bf[4], a0, a1;

    // ---- prologue
    stage_tile(0, 0);
    WAITV(0);
    SCHED0(); BARS();

    for (int t = 0; t < NK; ++t) {
        const int buf   = (t & 1) * 16384;
        const int abase = buf;
        const int bbase = buf + 8192;

        {   // stage tile t+1 into the other buffer (clamped tail, idempotent)
            const int v = t + 1 > NK - 1 ? NK - 1 : t + 1;
            stage_tile(v, (~t & 1) * 16384);
        }

#pragma unroll
        for (int n = 0; n < 4; ++n) bf[n] = rdfrag(bbase, wc * 64 + n * 16 + fr);
        a0 = rdfrag(abase, wr * 64 + fr);   // m=0
#pragma unroll
        for (int m = 0; m < 4; ++m) {
            if (m + 1 < 4) a1 = rdfrag(abase, wr * 64 + (m + 1) * 16 + fr);
            __builtin_amdgcn_s_setprio(1);
#pragma unroll
            for (int n = 0; n < 4; ++n)
                acc[m][n] = __builtin_amdgcn_mfma_scale_f32_16x16x128_f8f6f4(
                    mk8(a0), mk8(bf[n]), acc[m][n],
                    4, 4,                    // cbsz = blgp = 4 -> fp4 e2m1
                    0, 0x7f7f7f7f,           // scale A = 1.0 (e8m0)
                    0, 0x7f7f7f7f);          // scale B = 1.0
            __builtin_amdgcn_s_setprio(0);
            a0 = a1;
        }
        LGKM0();    // own buf(t) reads drained (WAR vs stage(t+2) next iter)
        WAITV(0);   // tile t+1's DMA landed
        SCHED0(); BARS();
    }

    // Epilogue: C/D col = lane&15, row = (lane>>4)*4 + reg (shape-determined).
    // Reduce s^2, s*xd, xd^2 over fr; 1 atomicAdd/row/qty/wave.
#pragma unroll
    for (int m = 0; m < 4; ++m) {
#pragma unroll
        for (int jj = 0; jj < 4; ++jj) {
            const int row = brow + wr * 64 + m * 16 + fq * 4 + jj;
            const float* xp = xdot + (size_t)row * DTOT + bcol + wc * 64 + fr;
            float pns = 0.f, psx = 0.f, pxx = 0.f;
#pragma unroll
            for (int n = 0; n < 4; ++n) {
                float s  = acc[m][n][jj];   // = 64 * s_true
                float xv = xp[n * 16];
                pns += s * s; psx += s * xv; pxx += xv * xv;
            }
#pragma unroll
            for (int msk = 1; msk < 16; msk <<= 1) {
                pns += __shfl_xor(pns, msk);
                psx += __shfl_xor(psx, msk);
                pxx += __shfl_xor(pxx, msk);
            }
            if (fr == 0) {
                atomicAdd(&ns_acc[row], pns);
                atomicAdd(&sx_acc[row], psx);
                atomicAdd(&xx_acc[row], pxx);
            }
        }
    }
}

__global__ void finalize_k(const float* __restrict__ ns, const float* __restrict__ sx,
                           const float* __restrict__ xx, float* __restrict__ out) {
    int i = blockIdx.x * blockDim.x + threadIdx.x;
    // ns,sx carry the x64 W-prescale: sx_true^2/(1+ns_true) = sx^2/(4096+ns)
    if (i < MTOT) out[i] = xx[i] - (sx[i] * sx[i]) / (4096.0f + ns[i]);
}

extern "C" void kernel_launch(void* const* d_in, const int* in_sizes, int n_in,
                              void* d_out, int out_size, void* d_ws, size_t ws_size,
                              hipStream_t stream) {
    const float* x  = (const float*)d_in[0];
    const float* xd = (const float*)d_in[1];
    const float* W  = (const float*)d_in[2];
    float* out = (float*)d_out;

    const size_t xq_bytes = (size_t)MTOT * DTOT / 2;   // 16.8 MB fp4
    const size_t wq_bytes = (size_t)DTOT * DTOT / 2;   //  2.1 MB fp4

    u8* xq = (u8*)d_ws;
    u8* wq = (u8*)((char*)d_ws + xq_bytes);
    float* accs = (float*)((char*)d_ws + xq_bytes + wq_bytes);
    float* nsA = accs;
    float* sxA = accs + MTOT;
    float* xxA = accs + 2 * MTOT;
    (void)ws_size; (void)in_sizes; (void)n_in; (void)out_size;

    const int nx8 = MTOT * DTOT / 8, nw8 = DTOT * DTOT / 8;
    cast4two_kernel<<<2048, 256, 0, stream>>>(x, W, (unsigned*)xq, (unsigned*)wq,
                                              accs, 3 * MTOT, nx8, nx8 + nw8);
    gemmf4<<<2048, 256, 0, stream>>>(xq, wq, xd, nsA, sxA, xxA);
    finalize_k<<<MTOT / 256, 256, 0, stream>>>(nsA, sxA, xxA, out);
}